// Round 21
// baseline (1373.830 us; speedup 1.0000x reference)
//
#include <hip/hip_runtime.h>

// ---------------------------------------------------------------------------
// BBCU binary SR network, round 32.
// R31 landed (1500 -> 1175; binw_pack2 131 -> ~6us, absmax improved to
// 0.0078). Remaining soft target: upoc (5 x ~83us; VALU floor ~11us) is
// latency-bound on its 18KB weight staging. Structural fact: each block
// covers 64 CONSECUTIVE output px in ONE row -> dr = ogy&1 is block-
// uniform -> only 2 of 4 subpixels occur -> HALF the staged weights are
// dead. This round stages the compact half (1152 u64, kd = k*2+dc index;
// params 128 entries). Consumed values bit-identical. LDS 23.5 -> ~14KB.
// body/hrcl/head/binw: R31 verbatim.
// ws: A0[0,16) A1[16,32)(body pong, dead before up1) Pbat[16,80) U[80,144)
//     bits/weights[144,..)
// ---------------------------------------------------------------------------

typedef unsigned long long u64;
typedef unsigned int u32;
typedef unsigned short u16;
typedef unsigned char u8;

__device__ inline float fadd(float a, float b) { return __fadd_rn(a, b); }
__device__ inline float fmul(float a, float b) { return __fmul_rn(a, b); }

// spread 16-bit x so bit j lands at bit 4j
__device__ inline u64 spread4(u64 x) {
  x &= 0xFFFFULL;
  x = (x | (x << 24)) & 0x000000FF000000FFULL;
  x = (x | (x << 12)) & 0x000F000F000F000FULL;
  x = (x | (x << 6))  & 0x0303030303030303ULL;
  x = (x | (x << 3))  & 0x1111111111111111ULL;
  return x;
}

// --- diagnostic ------------------------------------------------------------
__global__ __launch_bounds__(256) void diag_kernel(float* __restrict__ out,
                                                   int n, float tag) {
  int idx = blockIdx.x * 256 + threadIdx.x;
  if (idx < n) out[idx] = (idx == 0) ? tag : 0.f;
}

// --- weight prep v2: one wave per channel (R31-proven) ---------------------
__global__ __launch_bounds__(256) void binw_pack2_kernel(
    const float* __restrict__ w, u64* __restrict__ wbits,
    float* __restrict__ scale, int nch) {
  int ch = blockIdx.x * 4 + (threadIdx.x >> 6);
  int lane = threadIdx.x & 63;
  if (ch >= nch) return;
  const float* wc = w + (size_t)ch * 576 + lane * 9;
  float wv[9];
#pragma unroll
  for (int tap = 0; tap < 9; tap++) wv[tap] = wc[tap];
  float s = fabsf(wv[0]);
#pragma unroll
  for (int tap = 1; tap < 9; tap++) s = fadd(s, fabsf(wv[tap]));
#pragma unroll
  for (int m = 1; m < 64; m <<= 1) s = fadd(s, __shfl_xor(s, m));
  if (lane == 0) scale[ch] = __fdiv_rn(s, 576.0f);
#pragma unroll
  for (int tap = 0; tap < 9; tap++) {
    u64 mm = __ballot(wv[tap] > 0.0f);
    if (lane == 0) wbits[(size_t)ch * 9 + tap] = mm;
  }
}

// --- conv_first2: direct-NHWC conv_first + fused ballot pack (R29) ---------
__global__ __launch_bounds__(512, 8) void conv_first2_kernel(
    const float* __restrict__ x,      // (4,3,128,128)
    const float* __restrict__ w,      // (64,3,3,3) OIHW
    const float* __restrict__ b,
    const float* __restrict__ move,   // body_move[0]
    float* __restrict__ out,          // (4,16384,64) NHWC
    u64* __restrict__ bits) {         // (4,16384)
  __shared__ float s_w2[1728];        // [s][co], s = tap*3+ci
  __shared__ float s_bT[64], s_mvT[64];
  int t = threadIdx.x;
  for (int i = t; i < 1728; i += 512) {
    int s = i >> 6, co = i & 63;
    int tap = s / 3, ci = s - tap * 3;
    s_w2[i] = w[co * 27 + ci * 9 + tap];
  }
  if (t < 64) {
    int k = t >> 4, cq_ = t & 15;
    s_bT[t] = b[4 * cq_ + k];
    s_mvT[t] = move[4 * cq_ + k];
  }
  __syncthreads();

  int n = blockIdx.y;
  const float* xn = x + (size_t)n * 49152;
  float* on = out + (size_t)n * 1048576;
  u64* bo = bits + (size_t)n * 16384;
  int lane = t & 63;
  int pp = lane >> 4, cq = lane & 15;
  int pix = blockIdx.x * 32 + (t >> 6) * 4 + pp;
  int px = pix & 127, py = pix >> 7;

  float xv[27];
#pragma unroll
  for (int ky = 0; ky < 3; ky++) {
    int yy = py + ky - 1;
#pragma unroll
    for (int kx = 0; kx < 3; kx++) {
      int xx = px + kx - 1;
      bool ok = (yy >= 0 && yy < 128 && xx >= 0 && xx < 128);
#pragma unroll
      for (int ci = 0; ci < 3; ci++)
        xv[(ky * 3 + kx) * 3 + ci] =
            ok ? xn[ci * 16384 + yy * 128 + xx] : 0.0f;
    }
  }
  float vq[4];
  int sg[4];
#pragma unroll
  for (int k = 0; k < 4; k++) {
    int co = 4 * cq + k;
    float acc = 0.f;
#pragma unroll
    for (int s = 0; s < 27; s++)
      acc = fmaf(xv[s], s_w2[s * 64 + co], acc);
    int pi = k * 16 + cq;
    float wb = fadd(acc, s_bT[pi]);
    float r = wb >= 0.f ? wb : fmul(0.1f, wb);
    vq[k] = r;
    sg[k] = fadd(r, s_mvT[pi]) > 0.0f;
  }
  *(float4*)(on + (size_t)pix * 64 + 4 * cq) =
      make_float4(vq[0], vq[1], vq[2], vq[3]);
  u64 m0 = __ballot(sg[0]);
  u64 m1 = __ballot(sg[1]);
  u64 m2 = __ballot(sg[2]);
  u64 m3 = __ballot(sg[3]);
  if (cq == 0) {
    int sh = 16 * pp;
    bo[pix] = spread4(m0 >> sh) | (spread4(m1 >> sh) << 1) |
              (spread4(m2 >> sh) << 2) | (spread4(m3 >> sh) << 3);
  }
}

// --- body binary conv + rprelu + residual, NHWC output-centric (R29) -------
__global__ __launch_bounds__(512, 8) void body_kernel(
    const u64* __restrict__ bits_in,   // (4,16384)
    const float* __restrict__ feat,    // (4,16384,64) NHWC
    const u64* __restrict__ wbits,     // (64,9)
    const float* __restrict__ scale, const float* __restrict__ pa,
    const float* __restrict__ pb1, const float* __restrict__ pb2,
    const float* __restrict__ nmove,   // (64)
    float* __restrict__ out,           // (4,16384,64) NHWC
    u64* __restrict__ bits_out)        // (4,16384)
{
  __shared__ u64 s_w[576];            // [tap][k][cq]
  __shared__ u64 s_b[3 * 36];         // bits halo: 3 rows x 34 (pad 36)
  __shared__ float s_scT[64], s_aT[64], s_b1T[64], s_b2T[64], s_mvT[64];

  int t = threadIdx.x;
  int n = blockIdx.y;
  const u64* bin = bits_in + (size_t)n * 16384;

  int pix0 = blockIdx.x * 32;         // 32 consecutive px, single row
  int py = pix0 >> 7, px0 = pix0 & 127;

  for (int i = t; i < 576; i += 512) {
    int cq_ = i & 15, tk = i >> 4;
    int k = tk & 3, tap = tk >> 2;
    s_w[i] = wbits[(4 * cq_ + k) * 9 + tap];
  }
  for (int i = t; i < 102; i += 512) {
    int r = i / 34, c = i - r * 34;
    int yy = py - 1 + r, xx = px0 - 1 + c;
    s_b[r * 36 + c] = (yy >= 0 && yy < 128 && xx >= 0 && xx < 128)
                          ? bin[yy * 128 + xx] : 0ULL;
  }
  if (t < 64) {
    int k = t >> 4, cq_ = t & 15;
    int co = 4 * cq_ + k;
    s_scT[t] = scale[co]; s_aT[t] = pa[co];
    s_b1T[t] = pb1[co];   s_b2T[t] = pb2[co];
    s_mvT[t] = nmove[co];
  }
  __syncthreads();

  const float* fin = feat + (size_t)n * 1048576;
  float* outp = out + (size_t)n * 1048576;
  u64* bop = bits_out + (size_t)n * 16384;

  int lane = t & 63;
  int pp = lane >> 4, cq = lane & 15;
  int pl = (t >> 6) * 4 + pp;         // 0..31 local pixel
  int pix = pix0 + pl;
  int px = px0 + pl;

  u64 nb[9];
  int vf = 0, nvalid = 0;
#pragma unroll
  for (int ky = 0; ky < 3; ky++)
#pragma unroll
    for (int kx = 0; kx < 3; kx++) {
      int yy = py + ky - 1, xx = px + kx - 1;
      int tap = ky * 3 + kx;
      nb[tap] = s_b[ky * 36 + pl + kx];
      if (yy >= 0 && yy < 128 && xx >= 0 && xx < 128) {
        vf |= 1 << tap; nvalid++;
      }
    }
  bool interior = (vf == 511);
  int base = 64 * nvalid;

  float4 rv4 = *(const float4*)(fin + (size_t)pix * 64 + 4 * cq);
  float rv[4] = {rv4.x, rv4.y, rv4.z, rv4.w};

  float vq[4];
  int sg[4];
#pragma unroll
  for (int k = 0; k < 4; k++) {
    int c = 0;
#pragma unroll
    for (int tap = 0; tap < 9; tap++)
      c += __popcll(nb[tap] ^ s_w[(tap * 4 + k) * 16 + cq]);
    if (!interior) {
#pragma unroll
      for (int tap = 0; tap < 9; tap++)
        if (!((vf >> tap) & 1)) c -= __popcll(s_w[(tap * 4 + k) * 16 + cq]);
    }
    int sint = base - 2 * c;
    int pi = k * 16 + cq;
    float conv = fmul(s_scT[pi], (float)sint);
    float t1 = fadd(conv, s_b1T[pi]);
    float t2 = t1 >= 0.0f ? t1 : fmul(s_aT[pi], t1);
    float t3 = fadd(t2, s_b2T[pi]);
    float ov = fadd(t3, rv[k]);
    vq[k] = ov;
    sg[k] = fadd(ov, s_mvT[pi]) > 0.0f;
  }
  *(float4*)(outp + (size_t)pix * 64 + 4 * cq) =
      make_float4(vq[0], vq[1], vq[2], vq[3]);

  u64 m0 = __ballot(sg[0]);
  u64 m1 = __ballot(sg[1]);
  u64 m2 = __ballot(sg[2]);
  u64 m3 = __ballot(sg[3]);
  if (cq == 0) {
    int sh = 16 * pp;
    bop[pix] = spread4(m0 >> sh) | (spread4(m1 >> sh) << 1) |
               (spread4(m2 >> sh) << 2) | (spread4(m3 >> sh) << 3);
  }
}

// --- up conv, OUTPUT-centric; 64 px/block; block-uniform dr ----------------
// Block = 64 consecutive output px in ONE row -> dr = ogy&1 uniform ->
// stage only the 2 occurring subpixels: s_w[tap][kd][cq], kd = k*2+dc
// (1152 u64); params 128 entries. Consumed values identical to R31.
template <int W2>
__global__ __launch_bounds__(512, 8) void upoc_kernel(
    const u64* __restrict__ bits_in,   // (nz, W*W)
    const float* __restrict__ feat,    // (nz, W*W,64) NHWC
    const u64* __restrict__ wbits,     // (256,9)
    const float* __restrict__ scale, const float* __restrict__ pa,
    const float* __restrict__ pb1, const float* __restrict__ pb2,
    const float* __restrict__ nmove,   // (64) next layer's move
    float* __restrict__ out,           // (nz, W2*W2, 64) NHWC
    u64* __restrict__ bits_out)        // (nz, W2*W2) full u64
{
  constexpr int W = W2 / 2;
  constexpr int LOG2W2 = (W2 == 512) ? 9 : 8;
  constexpr size_t HWin = (size_t)W * W;
  constexpr size_t HWout = (size_t)W2 * W2;
  __shared__ u64 s_w[1152];           // [tap][kd][cq], kd = k*2+dc
  __shared__ u64 s_b[3 * 36];         // bits halo: 3 rows x 34 (pad 36)
  __shared__ float s_scT[128], s_aT[128], s_b1T[128], s_b2T[128], s_mv[64];

  int t = threadIdx.x;
  int n = blockIdx.z;
  const u64* bin = bits_in + (size_t)n * HWin;

  int opix0 = blockIdx.x * 64;        // 64 consecutive output px, one row
  int ogy0 = opix0 >> LOG2W2;
  int ogx0 = opix0 & (W2 - 1);
  int ipy0 = ogy0 >> 1, ipx0 = ogx0 >> 1;
  int dr = ogy0 & 1;                  // block-uniform subpixel row

  for (int i = t; i < 1152; i += 512) {
    int tap = i >> 7, r = i & 127;
    int cq_ = r & 15, kd = r >> 4;
    int k = kd >> 1, dc = kd & 1;
    int co = 16 * cq_ + 4 * k + 2 * dr + dc;
    s_w[i] = wbits[co * 9 + tap];
  }
  for (int i = t; i < 102; i += 512) {
    int r = i / 34, c = i - r * 34;
    int yy = ipy0 - 1 + r, xx = ipx0 - 1 + c;
    s_b[r * 36 + c] = (yy >= 0 && yy < W && xx >= 0 && xx < W)
                          ? bin[(size_t)yy * W + xx] : 0ULL;
  }
  for (int i = t; i < 128; i += 512) {
    int cq_ = i & 15, kd = i >> 4;
    int k = kd >> 1, dc = kd & 1;
    int co = 16 * cq_ + 4 * k + 2 * dr + dc;
    s_scT[i] = scale[co]; s_aT[i] = pa[co];
    s_b1T[i] = pb1[co];   s_b2T[i] = pb2[co];
  }
  if (t < 64) s_mv[t] = nmove[t];
  __syncthreads();

  const float* fin = feat + (size_t)n * 64 * HWin;
  float* op = out + (size_t)n * HWout * 64;
  u64* bop = bits_out + (size_t)n * HWout;

  int lane = t & 63;
  int pp = lane >> 4, cq = lane & 15;

#pragma unroll
  for (int g = 0; g < 2; g++) {
    int opix = opix0 + g * 32 + (t >> 6) * 4 + pp;
    int ogx = opix & (W2 - 1);
    int ipy = ipy0, ipx = ogx >> 1;
    int dc = ogx & 1;
    int sp = 2 * dr + dc;
    int dx = ipx - ipx0;                  // 0..31

    u64 nb[9];
    int vf = 0, nvalid = 0;
#pragma unroll
    for (int ky = 0; ky < 3; ky++)
#pragma unroll
      for (int kx = 0; kx < 3; kx++) {
        int yy = ipy + ky - 1, xx = ipx + kx - 1;
        int tap = ky * 3 + kx;
        nb[tap] = s_b[ky * 36 + dx + kx];
        if (yy >= 0 && yy < W && xx >= 0 && xx < W) {
          vf |= 1 << tap; nvalid++;
        }
      }
    bool interior = (vf == 511);
    int base = 64 * nvalid;
    size_t ipix = (size_t)ipy * W + ipx;

    // hoisted residual loads (overlap the popcount block)
    float rvv[4];
#pragma unroll
    for (int k = 0; k < 4; k++) {
      int rch = (16 * cq + 4 * k + sp) & 63;
      rvv[k] = fin[ipix * 64 + rch];
    }

    float vq[4];
    int sg[4];
#pragma unroll
    for (int k = 0; k < 4; k++) {
      int ochan = 4 * cq + k;
      int wi = (k * 2 + dc) * 16 + cq;     // compact transposed LDS index
      int c = 0;
#pragma unroll
      for (int tap = 0; tap < 9; tap++)
        c += __popcll(nb[tap] ^ s_w[tap * 128 + wi]);
      if (!interior) {
#pragma unroll
        for (int tap = 0; tap < 9; tap++)
          if (!((vf >> tap) & 1)) c -= __popcll(s_w[tap * 128 + wi]);
      }
      int sint = base - 2 * c;
      float conv = fmul(s_scT[wi], (float)sint);
      float t1 = fadd(conv, s_b1T[wi]);
      float t2 = t1 >= 0.0f ? t1 : fmul(s_aT[wi], t1);
      float t3 = fadd(t2, s_b2T[wi]);
      float ov = fadd(t3, rvv[k]);
      vq[k] = ov;
      sg[k] = fadd(ov, s_mv[ochan]) > 0.0f;
    }
    float4 v4 = make_float4(vq[0], vq[1], vq[2], vq[3]);
    *(float4*)(op + (size_t)opix * 64 + 4 * cq) = v4;

    u64 m0 = __ballot(sg[0]);
    u64 m1 = __ballot(sg[1]);
    u64 m2 = __ballot(sg[2]);
    u64 m3 = __ballot(sg[3]);
    if (cq == 0) {
      int sh = 16 * pp;
      u64 word = spread4(m0 >> sh) | (spread4(m1 >> sh) << 1) |
                 (spread4(m2 >> sh) << 2) | (spread4(m3 >> sh) << 3);
      bop[opix] = word;
    }
  }
}

// --- fused hr + conv_last, 16x4 tile; phase 2 = 8-lane ci split (R29) ------
__global__ __launch_bounds__(512, 4) void hrcl_kernel(
    const u64* __restrict__ bits,     // (512*512) packed U + hr_move
    const float* __restrict__ U,      // (512*512,64) NHWC, read-only
    const u64* __restrict__ hwb, const float* __restrict__ hsc,
    const float* __restrict__ ha, const float* __restrict__ hb1,
    const float* __restrict__ hb2,
    const float* __restrict__ clw, const float* __restrict__ clb,
    const float* __restrict__ x,      // (3,128,128) this sample
    float* __restrict__ out) {        // (3,512,512) this sample
  __shared__ __align__(16) float s_v[108 * 68];  // [halo px][68: 64ch+pad]
  __shared__ u64 s_hw[576];                      // [tap][k][cq]
  __shared__ u64 s_b[8 * 20];                    // bits: y0-2..y0+5, x0-2..
  __shared__ float s_scT[64], s_aT[64], s_b1T[64], s_b2T[64];
  __shared__ __align__(16) float s_cw[1728];     // [tap][co][ci]
  __shared__ float s_cb[3];

  int t = threadIdx.x;
  int x0 = blockIdx.x * 16, y0 = blockIdx.y * 4;

  for (int i = t; i < 576; i += 512) {
    int cq_ = i & 15, tk = i >> 4;
    int k = tk & 3, tap = tk >> 2;
    s_hw[i] = hwb[(4 * cq_ + k) * 9 + tap];
  }
  for (int i = t; i < 160; i += 512) {
    int r = i / 20, c = i - r * 20;
    int yy = y0 - 2 + r, xx = x0 - 2 + c;
    s_b[i] = (yy >= 0 && yy < 512 && xx >= 0 && xx < 512)
                 ? bits[(size_t)yy * 512 + xx] : 0ULL;
  }
  if (t < 64) {                       // [k][cq] transposed params
    int k = t >> 4, cq_ = t & 15;
    int co = 4 * cq_ + k;
    s_scT[t] = hsc[co]; s_aT[t] = ha[co];
    s_b1T[t] = hb1[co]; s_b2T[t] = hb2[co];
  }
  for (int i = t; i < 1728; i += 512) {
    int tap = i / 192, r = i - tap * 192;
    int co = r >> 6, ci = r & 63;
    s_cw[i] = clw[co * 576 + ci * 9 + tap];
  }
  if (t < 3) s_cb[t] = clb[t];
  __syncthreads();

  // ---- phase 1: hr on the 18x6 halo, V (leaky-applied) into LDS -----------
  for (int i = t; i < 1728; i += 512) {
    int cq = i & 15, hpx = i >> 4;
    int hrow = hpx / 18, hcol = hpx - hrow * 18;
    int gy = y0 - 1 + hrow, gx = x0 - 1 + hcol;
    float vq[4] = {0.f, 0.f, 0.f, 0.f};
    if (gy >= 0 && gy < 512 && gx >= 0 && gx < 512) {
      u64 nb[9];
      int vf = 0, nvalid = 0;
#pragma unroll
      for (int ky = 0; ky < 3; ky++)
#pragma unroll
        for (int kx = 0; kx < 3; kx++) {
          int yy = gy + ky - 1, xx = gx + kx - 1;
          int tap = ky * 3 + kx;
          nb[tap] = s_b[(hrow + ky) * 20 + hcol + kx];
          if (yy >= 0 && yy < 512 && xx >= 0 && xx < 512) {
            vf |= 1 << tap; nvalid++;
          }
        }
      bool interior = (vf == 511);
      int base = 64 * nvalid;
      float4 uv = *(const float4*)(U + ((size_t)gy * 512 + gx) * 64 + 4 * cq);
      float us[4] = {uv.x, uv.y, uv.z, uv.w};
#pragma unroll
      for (int k = 0; k < 4; k++) {
        int c = 0;
#pragma unroll
        for (int tap = 0; tap < 9; tap++)
          c += __popcll(nb[tap] ^ s_hw[(tap * 4 + k) * 16 + cq]);
        if (!interior) {
#pragma unroll
          for (int tap = 0; tap < 9; tap++)
            if (!((vf >> tap) & 1))
              c -= __popcll(s_hw[(tap * 4 + k) * 16 + cq]);
        }
        int sint = base - 2 * c;
        int pi = k * 16 + cq;
        float conv = fmul(s_scT[pi], (float)sint);
        float t1 = fadd(conv, s_b1T[pi]);
        float t2 = t1 >= 0.0f ? t1 : fmul(s_aT[pi], t1);
        float t3 = fadd(t2, s_b2T[pi]);
        float ov = fadd(t3, us[k]);
        vq[k] = ov >= 0.0f ? ov : fmul(0.1f, ov);      // leaky pre-applied
      }
    }
    *(float4*)(s_v + hpx * 68 + 4 * cq) =
        make_float4(vq[0], vq[1], vq[2], vq[3]);
  }
  __syncthreads();

  // ---- phase 2: conv_last, 8-lane ci split, single pass -------------------
  int lane = t & 63, wave = t >> 6;
  int pp8 = lane >> 3;               // 0..7 px within wave
  int cq3 = lane & 7;                // ci octant
  int p = wave * 8 + pp8;            // 0..63 within 16x4 tile
  int pr = p >> 4, pc = p & 15;
  float a0 = 0.f, a1 = 0.f, a2 = 0.f;
#pragma unroll
  for (int ky = 0; ky < 3; ky++)
#pragma unroll
    for (int kx = 0; kx < 3; kx++) {
      int tap = ky * 3 + kx;
      int hp = (pr + ky) * 18 + (pc + kx);
      const float* vp = s_v + hp * 68 + cq3 * 8;
      float4 va = *(const float4*)(vp);
      float4 vb = *(const float4*)(vp + 4);
      const float* w0p = s_cw + (tap * 3 + 0) * 64 + cq3 * 8;
      const float* w1p = s_cw + (tap * 3 + 1) * 64 + cq3 * 8;
      const float* w2p = s_cw + (tap * 3 + 2) * 64 + cq3 * 8;
      float4 w0a = *(const float4*)(w0p), w0b = *(const float4*)(w0p + 4);
      float4 w1a = *(const float4*)(w1p), w1b = *(const float4*)(w1p + 4);
      float4 w2a = *(const float4*)(w2p), w2b = *(const float4*)(w2p + 4);
      a0 = fmaf(va.x, w0a.x, a0); a0 = fmaf(va.y, w0a.y, a0);
      a0 = fmaf(va.z, w0a.z, a0); a0 = fmaf(va.w, w0a.w, a0);
      a0 = fmaf(vb.x, w0b.x, a0); a0 = fmaf(vb.y, w0b.y, a0);
      a0 = fmaf(vb.z, w0b.z, a0); a0 = fmaf(vb.w, w0b.w, a0);
      a1 = fmaf(va.x, w1a.x, a1); a1 = fmaf(va.y, w1a.y, a1);
      a1 = fmaf(va.z, w1a.z, a1); a1 = fmaf(va.w, w1a.w, a1);
      a1 = fmaf(vb.x, w1b.x, a1); a1 = fmaf(vb.y, w1b.y, a1);
      a1 = fmaf(vb.z, w1b.z, a1); a1 = fmaf(vb.w, w1b.w, a1);
      a2 = fmaf(va.x, w2a.x, a2); a2 = fmaf(va.y, w2a.y, a2);
      a2 = fmaf(va.z, w2a.z, a2); a2 = fmaf(va.w, w2a.w, a2);
      a2 = fmaf(vb.x, w2b.x, a2); a2 = fmaf(vb.y, w2b.y, a2);
      a2 = fmaf(vb.z, w2b.z, a2); a2 = fmaf(vb.w, w2b.w, a2);
    }
  // deterministic 8-lane butterfly reduce
#pragma unroll
  for (int m = 1; m < 8; m <<= 1) {
    a0 = fadd(a0, __shfl_xor(a0, m));
    a1 = fadd(a1, __shfl_xor(a1, m));
    a2 = fadd(a2, __shfl_xor(a2, m));
  }
  if (cq3 == 0) {
    int ogx = x0 + pc, ogy = y0 + pr;
    float o0 = fadd(a0, s_cb[0]);
    float o1 = fadd(a1, s_cb[1]);
    float o2 = fadd(a2, s_cb[2]);
    float sy = (ogy + 0.5f) * 0.25f - 0.5f;
    float sx = (ogx + 0.5f) * 0.25f - 0.5f;
    int iy0 = (int)floorf(sy);
    int ix0 = (int)floorf(sx);
    float fy = sy - (float)iy0, fx = sx - (float)ix0;
    int y0c = min(max(iy0, 0), 127), y1c = min(max(iy0 + 1, 0), 127);
    int x0c = min(max(ix0, 0), 127), x1c = min(max(ix0 + 1, 0), 127);
    float accs[3] = {o0, o1, o2};
#pragma unroll
    for (int co = 0; co < 3; co++) {
      const float* xp = x + (size_t)co * 16384;
      float c00 = xp[y0c * 128 + x0c], c01 = xp[y0c * 128 + x1c];
      float c10 = xp[y1c * 128 + x0c], c11 = xp[y1c * 128 + x1c];
      float v0, v1;
      if (y1c == y0c) { v0 = fmul(1.f, c00); v1 = fmul(1.f, c01); }
      else {
        v0 = fadd(fmul(1.f - fy, c00), fmul(fy, c10));
        v1 = fadd(fmul(1.f - fy, c01), fmul(fy, c11));
      }
      float base = (x1c == x0c) ? fmul(1.f, v0)
                                : fadd(fmul(1.f - fx, v0), fmul(fx, v1));
      out[((size_t)co << 18) + ((size_t)ogy << 9) + ogx] =
          fadd(accs[co], base);
    }
  }
}

extern "C" void kernel_launch(void* const* d_in, const int* in_sizes, int n_in,
                              void* d_out, int out_size, void* d_ws,
                              size_t ws_size, hipStream_t stream) {
  const float* x         = (const float*)d_in[0];
  const float* cf_w      = (const float*)d_in[1];
  const float* cf_b      = (const float*)d_in[2];
  const float* body_move = (const float*)d_in[3];
  const float* body_w    = (const float*)d_in[4];
  const float* body_a    = (const float*)d_in[5];
  const float* body_b1   = (const float*)d_in[6];
  const float* body_b2   = (const float*)d_in[7];
  const float* up1_move  = (const float*)d_in[8];
  const float* up1_w     = (const float*)d_in[9];
  const float* up1_a     = (const float*)d_in[10];
  const float* up1_b1    = (const float*)d_in[11];
  const float* up1_b2    = (const float*)d_in[12];
  const float* up2_move  = (const float*)d_in[13];
  const float* up2_w     = (const float*)d_in[14];
  const float* up2_a     = (const float*)d_in[15];
  const float* up2_b1    = (const float*)d_in[16];
  const float* up2_b2    = (const float*)d_in[17];
  const float* hr_move   = (const float*)d_in[18];
  const float* hr_w      = (const float*)d_in[19];
  const float* hr_a      = (const float*)d_in[20];
  const float* hr_b1     = (const float*)d_in[21];
  const float* hr_b2     = (const float*)d_in[22];
  const float* cl_w      = (const float*)d_in[23];
  const float* cl_b      = (const float*)d_in[24];
  float* out = (float*)d_out;

  const size_t M = 1024 * 1024;
  if (ws_size < 160 * M) {
    diag_kernel<<<(out_size + 255) / 256, 256, 0, stream>>>(
        out, out_size, (float)(ws_size >> 20));
    return;
  }

  char* ws = (char*)d_ws;
  float* A0    = (float*)(ws + 0);         // (4,16384,64) NHWC ping, 16M
  float* A1    = (float*)(ws + 16 * M);    // NHWC pong
  float* Pbat  = (float*)(ws + 16 * M);    // (4,256*256,64) NHWC, 64M
                                           //   (overwrites dead A1)
  float* U     = (float*)(ws + 80 * M);    // (512*512,64) NHWC per-sample
  u64* bitsA   = (u64*)(ws + 144 * M);     // (4,16384) 512K
  u64* bitsB   = (u64*)(ws + 144 * M + 512 * 1024);
  u64* bits256 = (u64*)(ws + 145 * M);     // (4,65536) 2M
  u64* bits512 = (u64*)(ws + 147 * M);     // (512*512) 2M per-sample
  u64* wbits   = (u64*)(ws + 149 * M);     // 2624*9 u64
  float* scales = (float*)(ws + 150 * M);  // 2624 f32

  // weight prep (wave-per-channel)
  binw_pack2_kernel<<<512, 256, 0, stream>>>(body_w, wbits, scales, 2048);
  binw_pack2_kernel<<<64, 256, 0, stream>>>(up1_w, wbits + (size_t)2048 * 9,
                                            scales + 2048, 256);
  binw_pack2_kernel<<<64, 256, 0, stream>>>(up2_w, wbits + (size_t)2304 * 9,
                                            scales + 2304, 256);
  binw_pack2_kernel<<<16, 256, 0, stream>>>(hr_w, wbits + (size_t)2560 * 9,
                                            scales + 2560, 64);

  // head: direct-NHWC conv_first + fused pack (one dispatch)
  conv_first2_kernel<<<dim3(512, 4), 512, 0, stream>>>(
      x, cf_w, cf_b, body_move, A0, bitsA);

  // body: 32 BBCU layers, NHWC output-centric, batched over samples
  float* fin = A0;
  float* fout = A1;
  u64* bbin = bitsA;
  u64* bbout = bitsB;
  for (int u = 0; u < 32; u++) {
    const float* nm = (u < 31) ? body_move + (u + 1) * 64 : up1_move;
    body_kernel<<<dim3(512, 4), 512, 0, stream>>>(
        bbin, fin, wbits + (size_t)u * 576, scales + u * 64,
        body_a + u * 64, body_b1 + u * 64, body_b2 + u * 64, nm,
        fout, bbout);
    float* tf = fin; fin = fout; fout = tf;
    u64* tb = bbin; bbin = bbout; bbout = tb;
  }
  // body out in A0 (even swap count), bits (packed w/ up1_move) in bitsA

  // up1 batched, NHWC residual: A0 -> Pbat + bits256 (u64); 64 px/block
  upoc_kernel<256><<<dim3(1024, 1, 4), 512, 0, stream>>>(
      bitsA, A0, wbits + (size_t)2048 * 9, scales + 2048,
      up1_a, up1_b1, up1_b2, up2_move, Pbat, bits256);

  // per sample: up2 -> fused hr+conv_last
  for (int n = 0; n < 4; n++) {
    // up2 output-centric: NHWC res P[n] -> NHWC U + bits512; 64 px/block
    upoc_kernel<512><<<dim3(4096, 1, 1), 512, 0, stream>>>(
        bits256 + (size_t)n * 65536, Pbat + (size_t)n * 4194304,
        wbits + (size_t)2304 * 9, scales + 2304,
        up2_a, up2_b1, up2_b2, hr_move, U, bits512);
    // fused hr + conv_last + bilinear base (16x4 tiles, 8-lane phase 2)
    hrcl_kernel<<<dim3(32, 128), 512, 0, stream>>>(
        bits512, U, wbits + (size_t)2560 * 9, scales + 2560,
        hr_a, hr_b1, hr_b2, cl_w, cl_b,
        x + (size_t)n * 49152, out + (size_t)n * 786432);
  }
}

// Round 22
// 1171.518 us; speedup vs baseline: 1.1727x; 1.1727x over previous
//
#include <hip/hip_runtime.h>

// ---------------------------------------------------------------------------
// BBCU binary SR network, round 33 = exact revert to R31 (best: 1175us).
// R32 post-mortem: upoc compact staging regressed (1175 -> 1374); upoc is
// BW-bound (326MB/dispatch @ 3.3TB/s), not staging-latency-bound, and the
// restructure perturbed the memory stream negatively. Restored R31:
//   * binw_pack2: wave-per-channel weight prep (~6us total).
//   * conv_first2: direct-NHWC head + fused ballot pack (1 dispatch).
//   * body: NHWC output-centric, 32 px/block, LDS bits halo, 512thr.
//   * upoc: 64 px/block, full [tap][ksp][cq] staging (R29/R31 form).
//   * hrcl: fused hr+conv_last, 16x4 tile, 8-lane ci-split phase 2.
// ws: A0[0,16) A1[16,32)(body pong, dead before up1) Pbat[16,80) U[80,144)
//     bits/weights[144,..)
// ---------------------------------------------------------------------------

typedef unsigned long long u64;
typedef unsigned int u32;
typedef unsigned short u16;
typedef unsigned char u8;

__device__ inline float fadd(float a, float b) { return __fadd_rn(a, b); }
__device__ inline float fmul(float a, float b) { return __fmul_rn(a, b); }

// spread 16-bit x so bit j lands at bit 4j
__device__ inline u64 spread4(u64 x) {
  x &= 0xFFFFULL;
  x = (x | (x << 24)) & 0x000000FF000000FFULL;
  x = (x | (x << 12)) & 0x000F000F000F000FULL;
  x = (x | (x << 6))  & 0x0303030303030303ULL;
  x = (x | (x << 3))  & 0x1111111111111111ULL;
  return x;
}

// --- diagnostic ------------------------------------------------------------
__global__ __launch_bounds__(256) void diag_kernel(float* __restrict__ out,
                                                   int n, float tag) {
  int idx = blockIdx.x * 256 + threadIdx.x;
  if (idx < n) out[idx] = (idx == 0) ? tag : 0.f;
}

// --- weight prep v2: one wave per channel (R31-proven) ---------------------
__global__ __launch_bounds__(256) void binw_pack2_kernel(
    const float* __restrict__ w, u64* __restrict__ wbits,
    float* __restrict__ scale, int nch) {
  int ch = blockIdx.x * 4 + (threadIdx.x >> 6);
  int lane = threadIdx.x & 63;
  if (ch >= nch) return;
  const float* wc = w + (size_t)ch * 576 + lane * 9;
  float wv[9];
#pragma unroll
  for (int tap = 0; tap < 9; tap++) wv[tap] = wc[tap];
  float s = fabsf(wv[0]);
#pragma unroll
  for (int tap = 1; tap < 9; tap++) s = fadd(s, fabsf(wv[tap]));
#pragma unroll
  for (int m = 1; m < 64; m <<= 1) s = fadd(s, __shfl_xor(s, m));
  if (lane == 0) scale[ch] = __fdiv_rn(s, 576.0f);
#pragma unroll
  for (int tap = 0; tap < 9; tap++) {
    u64 mm = __ballot(wv[tap] > 0.0f);
    if (lane == 0) wbits[(size_t)ch * 9 + tap] = mm;
  }
}

// --- conv_first2: direct-NHWC conv_first + fused ballot pack ---------------
__global__ __launch_bounds__(512, 8) void conv_first2_kernel(
    const float* __restrict__ x,      // (4,3,128,128)
    const float* __restrict__ w,      // (64,3,3,3) OIHW
    const float* __restrict__ b,
    const float* __restrict__ move,   // body_move[0]
    float* __restrict__ out,          // (4,16384,64) NHWC
    u64* __restrict__ bits) {         // (4,16384)
  __shared__ float s_w2[1728];        // [s][co], s = tap*3+ci
  __shared__ float s_bT[64], s_mvT[64];
  int t = threadIdx.x;
  for (int i = t; i < 1728; i += 512) {
    int s = i >> 6, co = i & 63;
    int tap = s / 3, ci = s - tap * 3;
    s_w2[i] = w[co * 27 + ci * 9 + tap];
  }
  if (t < 64) {
    int k = t >> 4, cq_ = t & 15;
    s_bT[t] = b[4 * cq_ + k];
    s_mvT[t] = move[4 * cq_ + k];
  }
  __syncthreads();

  int n = blockIdx.y;
  const float* xn = x + (size_t)n * 49152;
  float* on = out + (size_t)n * 1048576;
  u64* bo = bits + (size_t)n * 16384;
  int lane = t & 63;
  int pp = lane >> 4, cq = lane & 15;
  int pix = blockIdx.x * 32 + (t >> 6) * 4 + pp;
  int px = pix & 127, py = pix >> 7;

  float xv[27];
#pragma unroll
  for (int ky = 0; ky < 3; ky++) {
    int yy = py + ky - 1;
#pragma unroll
    for (int kx = 0; kx < 3; kx++) {
      int xx = px + kx - 1;
      bool ok = (yy >= 0 && yy < 128 && xx >= 0 && xx < 128);
#pragma unroll
      for (int ci = 0; ci < 3; ci++)
        xv[(ky * 3 + kx) * 3 + ci] =
            ok ? xn[ci * 16384 + yy * 128 + xx] : 0.0f;
    }
  }
  float vq[4];
  int sg[4];
#pragma unroll
  for (int k = 0; k < 4; k++) {
    int co = 4 * cq + k;
    float acc = 0.f;
#pragma unroll
    for (int s = 0; s < 27; s++)
      acc = fmaf(xv[s], s_w2[s * 64 + co], acc);
    int pi = k * 16 + cq;
    float wb = fadd(acc, s_bT[pi]);
    float r = wb >= 0.f ? wb : fmul(0.1f, wb);
    vq[k] = r;
    sg[k] = fadd(r, s_mvT[pi]) > 0.0f;
  }
  *(float4*)(on + (size_t)pix * 64 + 4 * cq) =
      make_float4(vq[0], vq[1], vq[2], vq[3]);
  u64 m0 = __ballot(sg[0]);
  u64 m1 = __ballot(sg[1]);
  u64 m2 = __ballot(sg[2]);
  u64 m3 = __ballot(sg[3]);
  if (cq == 0) {
    int sh = 16 * pp;
    bo[pix] = spread4(m0 >> sh) | (spread4(m1 >> sh) << 1) |
              (spread4(m2 >> sh) << 2) | (spread4(m3 >> sh) << 3);
  }
}

// --- body binary conv + rprelu + residual, NHWC output-centric -------------
__global__ __launch_bounds__(512, 8) void body_kernel(
    const u64* __restrict__ bits_in,   // (4,16384)
    const float* __restrict__ feat,    // (4,16384,64) NHWC
    const u64* __restrict__ wbits,     // (64,9)
    const float* __restrict__ scale, const float* __restrict__ pa,
    const float* __restrict__ pb1, const float* __restrict__ pb2,
    const float* __restrict__ nmove,   // (64)
    float* __restrict__ out,           // (4,16384,64) NHWC
    u64* __restrict__ bits_out)        // (4,16384)
{
  __shared__ u64 s_w[576];            // [tap][k][cq]
  __shared__ u64 s_b[3 * 36];         // bits halo: 3 rows x 34 (pad 36)
  __shared__ float s_scT[64], s_aT[64], s_b1T[64], s_b2T[64], s_mvT[64];

  int t = threadIdx.x;
  int n = blockIdx.y;
  const u64* bin = bits_in + (size_t)n * 16384;

  int pix0 = blockIdx.x * 32;         // 32 consecutive px, single row
  int py = pix0 >> 7, px0 = pix0 & 127;

  for (int i = t; i < 576; i += 512) {
    int cq_ = i & 15, tk = i >> 4;
    int k = tk & 3, tap = tk >> 2;
    s_w[i] = wbits[(4 * cq_ + k) * 9 + tap];
  }
  for (int i = t; i < 102; i += 512) {
    int r = i / 34, c = i - r * 34;
    int yy = py - 1 + r, xx = px0 - 1 + c;
    s_b[r * 36 + c] = (yy >= 0 && yy < 128 && xx >= 0 && xx < 128)
                          ? bin[yy * 128 + xx] : 0ULL;
  }
  if (t < 64) {
    int k = t >> 4, cq_ = t & 15;
    int co = 4 * cq_ + k;
    s_scT[t] = scale[co]; s_aT[t] = pa[co];
    s_b1T[t] = pb1[co];   s_b2T[t] = pb2[co];
    s_mvT[t] = nmove[co];
  }
  __syncthreads();

  const float* fin = feat + (size_t)n * 1048576;
  float* outp = out + (size_t)n * 1048576;
  u64* bop = bits_out + (size_t)n * 16384;

  int lane = t & 63;
  int pp = lane >> 4, cq = lane & 15;
  int pl = (t >> 6) * 4 + pp;         // 0..31 local pixel
  int pix = pix0 + pl;
  int px = px0 + pl;

  u64 nb[9];
  int vf = 0, nvalid = 0;
#pragma unroll
  for (int ky = 0; ky < 3; ky++)
#pragma unroll
    for (int kx = 0; kx < 3; kx++) {
      int yy = py + ky - 1, xx = px + kx - 1;
      int tap = ky * 3 + kx;
      nb[tap] = s_b[ky * 36 + pl + kx];
      if (yy >= 0 && yy < 128 && xx >= 0 && xx < 128) {
        vf |= 1 << tap; nvalid++;
      }
    }
  bool interior = (vf == 511);
  int base = 64 * nvalid;

  float4 rv4 = *(const float4*)(fin + (size_t)pix * 64 + 4 * cq);
  float rv[4] = {rv4.x, rv4.y, rv4.z, rv4.w};

  float vq[4];
  int sg[4];
#pragma unroll
  for (int k = 0; k < 4; k++) {
    int c = 0;
#pragma unroll
    for (int tap = 0; tap < 9; tap++)
      c += __popcll(nb[tap] ^ s_w[(tap * 4 + k) * 16 + cq]);
    if (!interior) {
#pragma unroll
      for (int tap = 0; tap < 9; tap++)
        if (!((vf >> tap) & 1)) c -= __popcll(s_w[(tap * 4 + k) * 16 + cq]);
    }
    int sint = base - 2 * c;
    int pi = k * 16 + cq;
    float conv = fmul(s_scT[pi], (float)sint);
    float t1 = fadd(conv, s_b1T[pi]);
    float t2 = t1 >= 0.0f ? t1 : fmul(s_aT[pi], t1);
    float t3 = fadd(t2, s_b2T[pi]);
    float ov = fadd(t3, rv[k]);
    vq[k] = ov;
    sg[k] = fadd(ov, s_mvT[pi]) > 0.0f;
  }
  *(float4*)(outp + (size_t)pix * 64 + 4 * cq) =
      make_float4(vq[0], vq[1], vq[2], vq[3]);

  u64 m0 = __ballot(sg[0]);
  u64 m1 = __ballot(sg[1]);
  u64 m2 = __ballot(sg[2]);
  u64 m3 = __ballot(sg[3]);
  if (cq == 0) {
    int sh = 16 * pp;
    bop[pix] = spread4(m0 >> sh) | (spread4(m1 >> sh) << 1) |
               (spread4(m2 >> sh) << 2) | (spread4(m3 >> sh) << 3);
  }
}

// --- up conv, OUTPUT-centric; 64 output px per block (2 groups) ------------
template <int W2>
__global__ __launch_bounds__(512, 8) void upoc_kernel(
    const u64* __restrict__ bits_in,   // (nz, W*W)
    const float* __restrict__ feat,    // (nz, W*W,64) NHWC
    const u64* __restrict__ wbits,     // (256,9)
    const float* __restrict__ scale, const float* __restrict__ pa,
    const float* __restrict__ pb1, const float* __restrict__ pb2,
    const float* __restrict__ nmove,   // (64) next layer's move
    float* __restrict__ out,           // (nz, W2*W2, 64) NHWC
    u64* __restrict__ bits_out)        // (nz, W2*W2) full u64
{
  constexpr int W = W2 / 2;
  constexpr int LOG2W2 = (W2 == 512) ? 9 : 8;
  constexpr size_t HWin = (size_t)W * W;
  constexpr size_t HWout = (size_t)W2 * W2;
  __shared__ u64 s_w[2304];           // [tap][ksp][cq]
  __shared__ u64 s_b[3 * 36];         // bits halo: 3 rows x 34 (pad 36)
  __shared__ float s_scT[256], s_aT[256], s_b1T[256], s_b2T[256], s_mv[64];

  int t = threadIdx.x;
  int n = blockIdx.z;
  const u64* bin = bits_in + (size_t)n * HWin;

  int opix0 = blockIdx.x * 64;        // 64 consecutive output px, one row
  int ogy0 = opix0 >> LOG2W2;
  int ogx0 = opix0 & (W2 - 1);
  int ipy0 = ogy0 >> 1, ipx0 = ogx0 >> 1;

  for (int i = t; i < 2304; i += 512) {
    int tap = i >> 8, r = i & 255;
    int cq_ = r & 15, ksp = r >> 4;
    int co = 16 * cq_ + 4 * (ksp >> 2) + (ksp & 3);
    s_w[i] = wbits[co * 9 + tap];
  }
  for (int i = t; i < 102; i += 512) {
    int r = i / 34, c = i - r * 34;
    int yy = ipy0 - 1 + r, xx = ipx0 - 1 + c;
    s_b[r * 36 + c] = (yy >= 0 && yy < W && xx >= 0 && xx < W)
                          ? bin[(size_t)yy * W + xx] : 0ULL;
  }
  for (int i = t; i < 256; i += 512) {
    int cq_ = i & 15, ksp = i >> 4;
    int co = 16 * cq_ + 4 * (ksp >> 2) + (ksp & 3);
    s_scT[i] = scale[co]; s_aT[i] = pa[co];
    s_b1T[i] = pb1[co];   s_b2T[i] = pb2[co];
  }
  if (t < 64) s_mv[t] = nmove[t];
  __syncthreads();

  const float* fin = feat + (size_t)n * 64 * HWin;
  float* op = out + (size_t)n * HWout * 64;
  u64* bop = bits_out + (size_t)n * HWout;

  int lane = t & 63;
  int pp = lane >> 4, cq = lane & 15;

#pragma unroll
  for (int g = 0; g < 2; g++) {
    int opix = opix0 + g * 32 + (t >> 6) * 4 + pp;
    int ogy = opix >> LOG2W2;
    int ogx = opix & (W2 - 1);
    int ipy = ogy >> 1, ipx = ogx >> 1;
    int sp = ((ogy & 1) << 1) | (ogx & 1);
    int dx = ipx - ipx0;                  // 0..31

    u64 nb[9];
    int vf = 0, nvalid = 0;
#pragma unroll
    for (int ky = 0; ky < 3; ky++)
#pragma unroll
      for (int kx = 0; kx < 3; kx++) {
        int yy = ipy + ky - 1, xx = ipx + kx - 1;
        int tap = ky * 3 + kx;
        nb[tap] = s_b[ky * 36 + dx + kx];
        if (yy >= 0 && yy < W && xx >= 0 && xx < W) {
          vf |= 1 << tap; nvalid++;
        }
      }
    bool interior = (vf == 511);
    int base = 64 * nvalid;
    size_t ipix = (size_t)ipy * W + ipx;

    // hoisted residual loads (overlap the popcount block)
    float rvv[4];
#pragma unroll
    for (int k = 0; k < 4; k++) {
      int rch = (16 * cq + 4 * k + sp) & 63;
      rvv[k] = fin[ipix * 64 + rch];
    }

    float vq[4];
    int sg[4];
#pragma unroll
    for (int k = 0; k < 4; k++) {
      int ochan = 4 * cq + k;
      int wi = (k * 4 + sp) * 16 + cq;     // transposed LDS index
      int c = 0;
#pragma unroll
      for (int tap = 0; tap < 9; tap++)
        c += __popcll(nb[tap] ^ s_w[tap * 256 + wi]);
      if (!interior) {
#pragma unroll
        for (int tap = 0; tap < 9; tap++)
          if (!((vf >> tap) & 1)) c -= __popcll(s_w[tap * 256 + wi]);
      }
      int sint = base - 2 * c;
      float conv = fmul(s_scT[wi], (float)sint);
      float t1 = fadd(conv, s_b1T[wi]);
      float t2 = t1 >= 0.0f ? t1 : fmul(s_aT[wi], t1);
      float t3 = fadd(t2, s_b2T[wi]);
      float ov = fadd(t3, rvv[k]);
      vq[k] = ov;
      sg[k] = fadd(ov, s_mv[ochan]) > 0.0f;
    }
    float4 v4 = make_float4(vq[0], vq[1], vq[2], vq[3]);
    *(float4*)(op + (size_t)opix * 64 + 4 * cq) = v4;

    u64 m0 = __ballot(sg[0]);
    u64 m1 = __ballot(sg[1]);
    u64 m2 = __ballot(sg[2]);
    u64 m3 = __ballot(sg[3]);
    if (cq == 0) {
      int sh = 16 * pp;
      u64 word = spread4(m0 >> sh) | (spread4(m1 >> sh) << 1) |
                 (spread4(m2 >> sh) << 2) | (spread4(m3 >> sh) << 3);
      bop[opix] = word;
    }
  }
}

// --- fused hr + conv_last, 16x4 tile; phase 2 = 8-lane ci split ------------
__global__ __launch_bounds__(512, 4) void hrcl_kernel(
    const u64* __restrict__ bits,     // (512*512) packed U + hr_move
    const float* __restrict__ U,      // (512*512,64) NHWC, read-only
    const u64* __restrict__ hwb, const float* __restrict__ hsc,
    const float* __restrict__ ha, const float* __restrict__ hb1,
    const float* __restrict__ hb2,
    const float* __restrict__ clw, const float* __restrict__ clb,
    const float* __restrict__ x,      // (3,128,128) this sample
    float* __restrict__ out) {        // (3,512,512) this sample
  __shared__ __align__(16) float s_v[108 * 68];  // [halo px][68: 64ch+pad]
  __shared__ u64 s_hw[576];                      // [tap][k][cq]
  __shared__ u64 s_b[8 * 20];                    // bits: y0-2..y0+5, x0-2..
  __shared__ float s_scT[64], s_aT[64], s_b1T[64], s_b2T[64];
  __shared__ __align__(16) float s_cw[1728];     // [tap][co][ci]
  __shared__ float s_cb[3];

  int t = threadIdx.x;
  int x0 = blockIdx.x * 16, y0 = blockIdx.y * 4;

  for (int i = t; i < 576; i += 512) {
    int cq_ = i & 15, tk = i >> 4;
    int k = tk & 3, tap = tk >> 2;
    s_hw[i] = hwb[(4 * cq_ + k) * 9 + tap];
  }
  for (int i = t; i < 160; i += 512) {
    int r = i / 20, c = i - r * 20;
    int yy = y0 - 2 + r, xx = x0 - 2 + c;
    s_b[i] = (yy >= 0 && yy < 512 && xx >= 0 && xx < 512)
                 ? bits[(size_t)yy * 512 + xx] : 0ULL;
  }
  if (t < 64) {                       // [k][cq] transposed params
    int k = t >> 4, cq_ = t & 15;
    int co = 4 * cq_ + k;
    s_scT[t] = hsc[co]; s_aT[t] = ha[co];
    s_b1T[t] = hb1[co]; s_b2T[t] = hb2[co];
  }
  for (int i = t; i < 1728; i += 512) {
    int tap = i / 192, r = i - tap * 192;
    int co = r >> 6, ci = r & 63;
    s_cw[i] = clw[co * 576 + ci * 9 + tap];
  }
  if (t < 3) s_cb[t] = clb[t];
  __syncthreads();

  // ---- phase 1: hr on the 18x6 halo, V (leaky-applied) into LDS -----------
  for (int i = t; i < 1728; i += 512) {
    int cq = i & 15, hpx = i >> 4;
    int hrow = hpx / 18, hcol = hpx - hrow * 18;
    int gy = y0 - 1 + hrow, gx = x0 - 1 + hcol;
    float vq[4] = {0.f, 0.f, 0.f, 0.f};
    if (gy >= 0 && gy < 512 && gx >= 0 && gx < 512) {
      u64 nb[9];
      int vf = 0, nvalid = 0;
#pragma unroll
      for (int ky = 0; ky < 3; ky++)
#pragma unroll
        for (int kx = 0; kx < 3; kx++) {
          int yy = gy + ky - 1, xx = gx + kx - 1;
          int tap = ky * 3 + kx;
          nb[tap] = s_b[(hrow + ky) * 20 + hcol + kx];
          if (yy >= 0 && yy < 512 && xx >= 0 && xx < 512) {
            vf |= 1 << tap; nvalid++;
          }
        }
      bool interior = (vf == 511);
      int base = 64 * nvalid;
      float4 uv = *(const float4*)(U + ((size_t)gy * 512 + gx) * 64 + 4 * cq);
      float us[4] = {uv.x, uv.y, uv.z, uv.w};
#pragma unroll
      for (int k = 0; k < 4; k++) {
        int c = 0;
#pragma unroll
        for (int tap = 0; tap < 9; tap++)
          c += __popcll(nb[tap] ^ s_hw[(tap * 4 + k) * 16 + cq]);
        if (!interior) {
#pragma unroll
          for (int tap = 0; tap < 9; tap++)
            if (!((vf >> tap) & 1))
              c -= __popcll(s_hw[(tap * 4 + k) * 16 + cq]);
        }
        int sint = base - 2 * c;
        int pi = k * 16 + cq;
        float conv = fmul(s_scT[pi], (float)sint);
        float t1 = fadd(conv, s_b1T[pi]);
        float t2 = t1 >= 0.0f ? t1 : fmul(s_aT[pi], t1);
        float t3 = fadd(t2, s_b2T[pi]);
        float ov = fadd(t3, us[k]);
        vq[k] = ov >= 0.0f ? ov : fmul(0.1f, ov);      // leaky pre-applied
      }
    }
    *(float4*)(s_v + hpx * 68 + 4 * cq) =
        make_float4(vq[0], vq[1], vq[2], vq[3]);
  }
  __syncthreads();

  // ---- phase 2: conv_last, 8-lane ci split, single pass -------------------
  int lane = t & 63, wave = t >> 6;
  int pp8 = lane >> 3;               // 0..7 px within wave
  int cq3 = lane & 7;                // ci octant
  int p = wave * 8 + pp8;            // 0..63 within 16x4 tile
  int pr = p >> 4, pc = p & 15;
  float a0 = 0.f, a1 = 0.f, a2 = 0.f;
#pragma unroll
  for (int ky = 0; ky < 3; ky++)
#pragma unroll
    for (int kx = 0; kx < 3; kx++) {
      int tap = ky * 3 + kx;
      int hp = (pr + ky) * 18 + (pc + kx);
      const float* vp = s_v + hp * 68 + cq3 * 8;
      float4 va = *(const float4*)(vp);
      float4 vb = *(const float4*)(vp + 4);
      const float* w0p = s_cw + (tap * 3 + 0) * 64 + cq3 * 8;
      const float* w1p = s_cw + (tap * 3 + 1) * 64 + cq3 * 8;
      const float* w2p = s_cw + (tap * 3 + 2) * 64 + cq3 * 8;
      float4 w0a = *(const float4*)(w0p), w0b = *(const float4*)(w0p + 4);
      float4 w1a = *(const float4*)(w1p), w1b = *(const float4*)(w1p + 4);
      float4 w2a = *(const float4*)(w2p), w2b = *(const float4*)(w2p + 4);
      a0 = fmaf(va.x, w0a.x, a0); a0 = fmaf(va.y, w0a.y, a0);
      a0 = fmaf(va.z, w0a.z, a0); a0 = fmaf(va.w, w0a.w, a0);
      a0 = fmaf(vb.x, w0b.x, a0); a0 = fmaf(vb.y, w0b.y, a0);
      a0 = fmaf(vb.z, w0b.z, a0); a0 = fmaf(vb.w, w0b.w, a0);
      a1 = fmaf(va.x, w1a.x, a1); a1 = fmaf(va.y, w1a.y, a1);
      a1 = fmaf(va.z, w1a.z, a1); a1 = fmaf(va.w, w1a.w, a1);
      a1 = fmaf(vb.x, w1b.x, a1); a1 = fmaf(vb.y, w1b.y, a1);
      a1 = fmaf(vb.z, w1b.z, a1); a1 = fmaf(vb.w, w1b.w, a1);
      a2 = fmaf(va.x, w2a.x, a2); a2 = fmaf(va.y, w2a.y, a2);
      a2 = fmaf(va.z, w2a.z, a2); a2 = fmaf(va.w, w2a.w, a2);
      a2 = fmaf(vb.x, w2b.x, a2); a2 = fmaf(vb.y, w2b.y, a2);
      a2 = fmaf(vb.z, w2b.z, a2); a2 = fmaf(vb.w, w2b.w, a2);
    }
  // deterministic 8-lane butterfly reduce
#pragma unroll
  for (int m = 1; m < 8; m <<= 1) {
    a0 = fadd(a0, __shfl_xor(a0, m));
    a1 = fadd(a1, __shfl_xor(a1, m));
    a2 = fadd(a2, __shfl_xor(a2, m));
  }
  if (cq3 == 0) {
    int ogx = x0 + pc, ogy = y0 + pr;
    float o0 = fadd(a0, s_cb[0]);
    float o1 = fadd(a1, s_cb[1]);
    float o2 = fadd(a2, s_cb[2]);
    float sy = (ogy + 0.5f) * 0.25f - 0.5f;
    float sx = (ogx + 0.5f) * 0.25f - 0.5f;
    int iy0 = (int)floorf(sy);
    int ix0 = (int)floorf(sx);
    float fy = sy - (float)iy0, fx = sx - (float)ix0;
    int y0c = min(max(iy0, 0), 127), y1c = min(max(iy0 + 1, 0), 127);
    int x0c = min(max(ix0, 0), 127), x1c = min(max(ix0 + 1, 0), 127);
    float accs[3] = {o0, o1, o2};
#pragma unroll
    for (int co = 0; co < 3; co++) {
      const float* xp = x + (size_t)co * 16384;
      float c00 = xp[y0c * 128 + x0c], c01 = xp[y0c * 128 + x1c];
      float c10 = xp[y1c * 128 + x0c], c11 = xp[y1c * 128 + x1c];
      float v0, v1;
      if (y1c == y0c) { v0 = fmul(1.f, c00); v1 = fmul(1.f, c01); }
      else {
        v0 = fadd(fmul(1.f - fy, c00), fmul(fy, c10));
        v1 = fadd(fmul(1.f - fy, c01), fmul(fy, c11));
      }
      float base = (x1c == x0c) ? fmul(1.f, v0)
                                : fadd(fmul(1.f - fx, v0), fmul(fx, v1));
      out[((size_t)co << 18) + ((size_t)ogy << 9) + ogx] =
          fadd(accs[co], base);
    }
  }
}

extern "C" void kernel_launch(void* const* d_in, const int* in_sizes, int n_in,
                              void* d_out, int out_size, void* d_ws,
                              size_t ws_size, hipStream_t stream) {
  const float* x         = (const float*)d_in[0];
  const float* cf_w      = (const float*)d_in[1];
  const float* cf_b      = (const float*)d_in[2];
  const float* body_move = (const float*)d_in[3];
  const float* body_w    = (const float*)d_in[4];
  const float* body_a    = (const float*)d_in[5];
  const float* body_b1   = (const float*)d_in[6];
  const float* body_b2   = (const float*)d_in[7];
  const float* up1_move  = (const float*)d_in[8];
  const float* up1_w     = (const float*)d_in[9];
  const float* up1_a     = (const float*)d_in[10];
  const float* up1_b1    = (const float*)d_in[11];
  const float* up1_b2    = (const float*)d_in[12];
  const float* up2_move  = (const float*)d_in[13];
  const float* up2_w     = (const float*)d_in[14];
  const float* up2_a     = (const float*)d_in[15];
  const float* up2_b1    = (const float*)d_in[16];
  const float* up2_b2    = (const float*)d_in[17];
  const float* hr_move   = (const float*)d_in[18];
  const float* hr_w      = (const float*)d_in[19];
  const float* hr_a      = (const float*)d_in[20];
  const float* hr_b1     = (const float*)d_in[21];
  const float* hr_b2     = (const float*)d_in[22];
  const float* cl_w      = (const float*)d_in[23];
  const float* cl_b      = (const float*)d_in[24];
  float* out = (float*)d_out;

  const size_t M = 1024 * 1024;
  if (ws_size < 160 * M) {
    diag_kernel<<<(out_size + 255) / 256, 256, 0, stream>>>(
        out, out_size, (float)(ws_size >> 20));
    return;
  }

  char* ws = (char*)d_ws;
  float* A0    = (float*)(ws + 0);         // (4,16384,64) NHWC ping, 16M
  float* A1    = (float*)(ws + 16 * M);    // NHWC pong
  float* Pbat  = (float*)(ws + 16 * M);    // (4,256*256,64) NHWC, 64M
                                           //   (overwrites dead A1)
  float* U     = (float*)(ws + 80 * M);    // (512*512,64) NHWC per-sample
  u64* bitsA   = (u64*)(ws + 144 * M);     // (4,16384) 512K
  u64* bitsB   = (u64*)(ws + 144 * M + 512 * 1024);
  u64* bits256 = (u64*)(ws + 145 * M);     // (4,65536) 2M
  u64* bits512 = (u64*)(ws + 147 * M);     // (512*512) 2M per-sample
  u64* wbits   = (u64*)(ws + 149 * M);     // 2624*9 u64
  float* scales = (float*)(ws + 150 * M);  // 2624 f32

  // weight prep (wave-per-channel)
  binw_pack2_kernel<<<512, 256, 0, stream>>>(body_w, wbits, scales, 2048);
  binw_pack2_kernel<<<64, 256, 0, stream>>>(up1_w, wbits + (size_t)2048 * 9,
                                            scales + 2048, 256);
  binw_pack2_kernel<<<64, 256, 0, stream>>>(up2_w, wbits + (size_t)2304 * 9,
                                            scales + 2304, 256);
  binw_pack2_kernel<<<16, 256, 0, stream>>>(hr_w, wbits + (size_t)2560 * 9,
                                            scales + 2560, 64);

  // head: direct-NHWC conv_first + fused pack (one dispatch)
  conv_first2_kernel<<<dim3(512, 4), 512, 0, stream>>>(
      x, cf_w, cf_b, body_move, A0, bitsA);

  // body: 32 BBCU layers, NHWC output-centric, batched over samples
  float* fin = A0;
  float* fout = A1;
  u64* bbin = bitsA;
  u64* bbout = bitsB;
  for (int u = 0; u < 32; u++) {
    const float* nm = (u < 31) ? body_move + (u + 1) * 64 : up1_move;
    body_kernel<<<dim3(512, 4), 512, 0, stream>>>(
        bbin, fin, wbits + (size_t)u * 576, scales + u * 64,
        body_a + u * 64, body_b1 + u * 64, body_b2 + u * 64, nm,
        fout, bbout);
    float* tf = fin; fin = fout; fout = tf;
    u64* tb = bbin; bbin = bbout; bbout = tb;
  }
  // body out in A0 (even swap count), bits (packed w/ up1_move) in bitsA

  // up1 batched, NHWC residual: A0 -> Pbat + bits256 (u64); 64 px/block
  upoc_kernel<256><<<dim3(1024, 1, 4), 512, 0, stream>>>(
      bitsA, A0, wbits + (size_t)2048 * 9, scales + 2048,
      up1_a, up1_b1, up1_b2, up2_move, Pbat, bits256);

  // per sample: up2 -> fused hr+conv_last
  for (int n = 0; n < 4; n++) {
    // up2 output-centric: NHWC res P[n] -> NHWC U + bits512; 64 px/block
    upoc_kernel<512><<<dim3(4096, 1, 1), 512, 0, stream>>>(
        bits256 + (size_t)n * 65536, Pbat + (size_t)n * 4194304,
        wbits + (size_t)2304 * 9, scales + 2304,
        up2_a, up2_b1, up2_b2, hr_move, U, bits512);
    // fused hr + conv_last + bilinear base (16x4 tiles, 8-lane phase 2)
    hrcl_kernel<<<dim3(32, 128), 512, 0, stream>>>(
        bits512, U, wbits + (size_t)2560 * 9, scales + 2560,
        hr_a, hr_b1, hr_b2, cl_w, cl_b,
        x + (size_t)n * 49152, out + (size_t)n * 786432);
  }
}